// Round 8
// baseline (87.424 us; speedup 1.0000x reference)
//
#include <hip/hip_runtime.h>
#include <hip/hip_bf16.h>

// KANLinear as fragment-direct bf16 MFMA GEMM, 2-dispatch, NO-SYNC fusion (R8):
//   y = hatA @ W''^T + skip_b
// R7 post-mortem: structure correct and NEUTRAL vs R2 (78.0 normalized) —
//   the saved dispatch gap + reduce kernel was eaten by gemm2 running
//   latency-bound: ring-4 prefetch = 4 kb-steps (~25 cyc MFMA) of lead vs
//   ~500-900 cyc IF$/HBM latency (Af is L2-flushed at prep2's kernel-end
//   release; first touch per XCD misses to L3). Step time ~ L/4 => ~20-25us.
// R8: ring-8 prefetch (16 in-flight 16B loads/wave). Step time ~ L/8 =>
//   gemm2 drops to its ~8-10us L2-BW floor. No other changes.
// Structure: prep materializes the FULL hat matrix Af (2048x4096 bf16,
//   16.8MB) in MFMA A-FRAGMENT order, redundancy-1. Gemm runs full-K 32x32
//   block tiles, NO LDS / barriers / partials / reduce / atomics (R1/R4/R5
//   sync mechanisms all empirically disqualified).
// Skip fold (verified R1-R7): sum_k hat_k(t)*grid_k = clamp(x) exactly =>
//   prep bakes W''[o][d*16+k] = values[o,d,k] + grid_k*skip_w[o,d], K=4096.
// Layouts (verified on HW):
//   A-frag chunk(kb,rp): lane l holds A[rp*16+(l&15)][kb*32+(l>>4)*8 ..+8]
//     uint4 index = kb*8192 + rp*64 + l
//   B-frag chunk(kb,cp): lane l holds W''[cp*16+(l&15)][kb*32+(l>>4)*8 ..+8]
//     uint4 index = kb*1024 + cp*64 + l
//   C/D: col = lane&15, row = (lane>>4)*4 + j
// Gemm grid: 64 mi x 8 nj = 512 blocks (2/CU); mi = bid&63 so nj-siblings
//   (sharing the A row-panel) are stride-64 => same XCD => A panel (2MB/XCD)
//   and Wf (2.1MB) stay L2-resident; L3 unique traffic ~34MB.

namespace {
constexpr int Bsz  = 2048;
constexpr int Din  = 256;
constexpr int Dout = 256;
constexpr int Kn   = 16;
constexpr int KKNOT = Din * Kn;        // 4096 = full K (skip folded in)
constexpr int KB    = KKNOT / 32;      // 128 k-blocks of 32
constexpr float INV_H = 7.5f;          // 1 / (2/15)
constexpr float Hgrid = 2.0f / 15.0f;
constexpr int RING  = 8;               // prefetch depth (kb-steps)
}

typedef __attribute__((ext_vector_type(8))) short shortx8;   // 8 bf16 = 4 VGPR
typedef __attribute__((ext_vector_type(4))) float floatx4;   // MFMA acc

__device__ __forceinline__ unsigned int f2bf(float f) {
  __hip_bfloat16 h = __float2bfloat16(f);
  return (unsigned int)*reinterpret_cast<unsigned short*>(&h);
}
__device__ __forceinline__ float clamp1(float v) {
  return fminf(1.f, fmaxf(-1.f, v));
}
// Pack two pre-rounded f32 bit patterns (already +0x8000) into bf16x2.
__device__ __forceinline__ unsigned int packbf(unsigned int e0, unsigned int e1) {
  return (e1 & 0xffff0000u) | (e0 >> 16);
}
__device__ __forceinline__ unsigned int rnd(float f) {
  return __float_as_uint(f) + 0x8000u;
}

// 8 hat weights for one dim (hats h0..h0+7) -> one 16B bf16x8 chunk.
__device__ __forceinline__ uint4 hat8(float xv, float h0) {
  const float t = (clamp1(xv) + 1.f) * INV_H;
  unsigned int e[8];
  #pragma unroll
  for (int h = 0; h < 8; ++h)
    e[h] = rnd(fmaxf(0.f, 1.f - fabsf(t - (h0 + (float)h))));
  return make_uint4(packbf(e[0], e[1]), packbf(e[2], e[3]),
                    packbf(e[4], e[5]), packbf(e[6], e[7]));
}

// --- Prep: (a) fold skip into values -> Wf in B-fragment order (1 chunk per
//     thread); (b) build full hat matrix -> Af in A-fragment order (8 chunks
//     per wave, redundancy-1). Grid: 512 blocks x 256 threads.
__global__ __launch_bounds__(256) void kan_prep2(
    const float* __restrict__ x, const float* __restrict__ values,
    const float* __restrict__ skip_w, unsigned short* __restrict__ Wf,
    unsigned short* __restrict__ Af) {
  const int tid = blockIdx.x * 256 + threadIdx.x;   // 131072 total
  // ---- Wf chunk: chunk(kb,og,q,n), thread -> one 16B chunk-lane ----
  {
    const int q  = tid & 3;
    const int n  = (tid >> 2) & 15;
    const int og = (tid >> 6) & 15;
    const int kb = tid >> 10;                        // 0..127
    const int o  = og * 16 + n;
    const int k0 = kb * 32 + q * 8;                  // 8 consecutive k, same dim
    const int d  = k0 >> 4;
    const float h0 = (float)(k0 & 15);               // 0 or 8
    const float sw = skip_w[o * Din + d];
    const float* src = values + (size_t)o * KKNOT + k0;
    const float4 v0 = *(const float4*)src;
    const float4 v1 = *(const float4*)(src + 4);
    float e[8] = {v0.x, v0.y, v0.z, v0.w, v1.x, v1.y, v1.z, v1.w};
    #pragma unroll
    for (int j = 0; j < 8; ++j)
      e[j] = fmaf(-1.f + (h0 + (float)j) * Hgrid, sw, e[j]);  // + grid_k*skip_w
    const size_t chunk = (size_t)kb * 1024 + og * 64 + q * 16 + n;
    *(uint4*)(Wf + chunk * 8) = make_uint4(
        f2bf(e[0]) | (f2bf(e[1]) << 16), f2bf(e[2]) | (f2bf(e[3]) << 16),
        f2bf(e[4]) | (f2bf(e[5]) << 16), f2bf(e[6]) | (f2bf(e[7]) << 16));
  }
  // ---- Af chunks: chunk(kb,rp) = kb*128 + rp; wave writes 1KB per chunk ----
  {
    const int lane  = threadIdx.x & 63;
    const int wslot = blockIdx.x * 4 + (threadIdx.x >> 6);  // 0..2047
    const int lrow  = lane & 15, lq = lane >> 4;
    uint4* A4 = (uint4*)Af;
    #pragma unroll
    for (int ci = 0; ci < 8; ++ci) {
      const int chunk = wslot * 8 + ci;              // 0..16383
      const int kb = chunk >> 7;                     // 0..127
      const int rp = chunk & 127;                    // row-panel (16 rows)
      const int row = rp * 16 + lrow;
      const int d   = kb * 2 + (lq >> 1);            // lq*8 within 32-k block
      const float h0 = (float)((lq & 1) * 8);
      const float xv = x[(size_t)row * Din + d];
      A4[(size_t)chunk * 64 + lane] = hat8(xv, h0);
    }
  }
}

// --- Full-K GEMM, no LDS, no barriers. Grid = 512 blocks x 256 thr (4 waves).
//     Block tile 32 rows x 32 cols; wave = 16x16 quadrant, full K chain.
//     Ring-8 register prefetch: 16 outstanding 16B loads per wave.
__global__ __launch_bounds__(256) void kan_gemm2(
    const unsigned short* __restrict__ Af, const unsigned short* __restrict__ Wf,
    const float* __restrict__ skip_b, float* __restrict__ out) {
  const int tid  = threadIdx.x;
  const int wave = tid >> 6, lane = tid & 63;
  const int mi   = blockIdx.x & 63;              // A-panel: nj-siblings same XCD
  const int nj   = blockIdx.x >> 6;              // 0..7
  const int wr   = wave >> 1, wc = wave & 1;
  const int rp   = mi * 2 + wr;                  // row-panel 0..127
  const int cp   = nj * 2 + wc;                  // out col-group 0..15

  const uint4* A4 = (const uint4*)Af;            // kb*8192 + rp*64 + lane
  const uint4* B4 = (const uint4*)Wf;            // kb*1024 + cp*64 + lane
  const size_t aoff = (size_t)rp * 64 + lane;
  const size_t boff = (size_t)cp * 64 + lane;

  union U { uint4 u; shortx8 s; };
  floatx4 accE = {}, accO = {};
  uint4 ar[RING], br[RING];

  // Prologue: fill the ring (kb 0..7).
  #pragma unroll
  for (int i = 0; i < RING; ++i) {
    ar[i] = A4[(size_t)i * 8192 + aoff];
    br[i] = B4[(size_t)i * 1024 + boff];
  }

  for (int kb = 0; kb < KB; kb += RING) {
    #pragma unroll
    for (int i = 0; i < RING; ++i) {           // i is compile-time after unroll
      U au, bu;
      au.u = ar[i]; bu.u = br[i];
      if (i & 1)
        accO = __builtin_amdgcn_mfma_f32_16x16x32_bf16(au.s, bu.s, accO, 0, 0, 0);
      else
        accE = __builtin_amdgcn_mfma_f32_16x16x32_bf16(au.s, bu.s, accE, 0, 0, 0);
      const int nk = kb + RING + i;
      if (nk < KB) {
        ar[i] = A4[(size_t)nk * 8192 + aoff];
        br[i] = B4[(size_t)nk * 1024 + boff];
      }
    }
  }

  // Epilogue: direct out + bias. C/D map: col=lane&15, row=(lane>>4)*4+j.
  const int col  = cp * 16 + (lane & 15);
  const int row0 = mi * 32 + wr * 16 + (lane >> 4) * 4;
  const float sb = skip_b[col];
  #pragma unroll
  for (int j = 0; j < 4; ++j)
    out[(size_t)(row0 + j) * Dout + col] = (accE[j] + accO[j]) + sb;
}

// ---------------- Fallback (round-1 structure, needs 4.4 MB ws) ----------------
__device__ __forceinline__ void knot_interp(float xraw, float& xv, float& w, int& l) {
  xv = fminf(1.0f, fmaxf(-1.0f, xraw));
  float t = (xv + 1.0f) * INV_H;
  l = (int)ceilf(t) - 1;
  l = l < 0 ? 0 : (l > Kn - 2 ? Kn - 2 : l);
  float g0 = -1.0f + Hgrid * (float)l;
  w = (xv - g0) * INV_H;
}

__global__ __launch_bounds__(256) void prep_transpose(
    const float* __restrict__ values, const float* __restrict__ skip_w,
    float* __restrict__ vt, float* __restrict__ swt) {
  int idx = blockIdx.x * blockDim.x + threadIdx.x;
  if (idx < Din * Kn * Dout) {
    int k = idx & (Kn - 1);
    int d = (idx >> 4) & (Din - 1);
    int o = idx >> 12;
    vt[(d * Kn + k) * Dout + o] = values[idx];
  }
  if (idx < Dout * Din) {
    int d = idx & (Din - 1);
    int o = idx >> 8;
    swt[d * Dout + o] = skip_w[idx];
  }
}

__global__ __launch_bounds__(256) void kan_main(
    const float* __restrict__ x, const float* __restrict__ vt,
    const float* __restrict__ swt, const float* __restrict__ skip_b,
    float* __restrict__ out) {
  __shared__ float s_w[4][Din];
  __shared__ float s_x[4][Din];
  __shared__ int   s_l[4][Din];
  const int tid = threadIdx.x;
  const int b0  = blockIdx.x * 4;
  for (int i = tid; i < 4 * Din; i += 256) {
    int bb = i >> 8;
    int d  = i & (Din - 1);
    float xv, w; int l;
    knot_interp(x[(b0 + bb) * Din + d], xv, w, l);
    s_w[bb][d] = w; s_x[bb][d] = xv; s_l[bb][d] = l;
  }
  __syncthreads();
  const int g = tid >> 6, lane = tid & 63;
  const int o = lane << 2, b = b0 + g;
  float4 acc = make_float4(0.f, 0.f, 0.f, 0.f);
  for (int d = 0; d < Din; ++d) {
    const float w = s_w[g][d], xv = s_x[g][d];
    const int l = s_l[g][d];
    const float* base = vt + (d * Kn + l) * Dout + o;
    const float4 vl = *(const float4*)(base);
    const float4 vr = *(const float4*)(base + Dout);
    const float4 sw = *(const float4*)(swt + d * Dout + o);
    acc.x = fmaf(xv, sw.x, fmaf(w, vr.x - vl.x, acc.x + vl.x));
    acc.y = fmaf(xv, sw.y, fmaf(w, vr.y - vl.y, acc.y + vl.y));
    acc.z = fmaf(xv, sw.z, fmaf(w, vr.z - vl.z, acc.z + vl.z));
    acc.w = fmaf(xv, sw.w, fmaf(w, vr.w - vl.w, acc.w + vl.w));
  }
  const float4 bias = *(const float4*)(skip_b + o);
  acc.x += bias.x; acc.y += bias.y; acc.z += bias.z; acc.w += bias.w;
  *(float4*)(out + (size_t)b * Dout + o) = acc;
}

extern "C" void kernel_launch(void* const* d_in, const int* in_sizes, int n_in,
                              void* d_out, int out_size, void* d_ws, size_t ws_size,
                              hipStream_t stream) {
  (void)in_sizes; (void)n_in; (void)out_size;
  const float* x      = (const float*)d_in[0];
  const float* values = (const float*)d_in[1];
  const float* skip_w = (const float*)d_in[2];
  const float* skip_b = (const float*)d_in[3];
  float* out = (float*)d_out;

  const size_t wf_bytes = (size_t)Dout * KKNOT * sizeof(unsigned short);   // 2.10 MB
  const size_t af_bytes = (size_t)Bsz * KKNOT * sizeof(unsigned short);    // 16.78 MB
  const size_t need2    = wf_bytes + af_bytes;                             // 18.9 MB
  const size_t need_fb  = (size_t)(Din * Kn * Dout + Din * Dout) * sizeof(float);

  if (ws_size >= need2) {
    unsigned short* Wf = (unsigned short*)d_ws;
    unsigned short* Af = (unsigned short*)((char*)d_ws + wf_bytes);
    kan_prep2<<<512, 256, 0, stream>>>(x, values, skip_w, Wf, Af);
    kan_gemm2<<<512, 256, 0, stream>>>(Af, Wf, skip_b, out);
  } else if (ws_size >= need_fb) {
    float* vt  = (float*)d_ws;
    float* swt = vt + Din * Kn * Dout;
    prep_transpose<<<(Din * Kn * Dout + 255) / 256, 256, 0, stream>>>(values, skip_w, vt, swt);
    kan_main<<<Bsz / 4, 256, 0, stream>>>(x, vt, swt, skip_b, out);
  }
}